// Round 1
// baseline (401.596 us; speedup 1.0000x reference)
//
#include <hip/hip_runtime.h>
#include <hip/hip_bf16.h>
#include <hip/hip_fp16.h>

#define IN_DIM 4096
#define OUT_DIM 4096
#define HAD_SCALE_F 0.08838834764831845f   // 2^-3.5

typedef _Float16 f16x4 __attribute__((ext_vector_type(4)));
typedef _Float16 f16x8 __attribute__((ext_vector_type(8)));
typedef float    f32x4 __attribute__((ext_vector_type(4)));

// ---------------------------------------------------------------------------
// Kernel A: per-row blockwise Hadamard (FWHT over 128-blocks), scale, f32
// rowsum, convert to fp16. One block (256 thr) per row of 4096 floats.
// ---------------------------------------------------------------------------
__global__ __launch_bounds__(256)
void had_rows(const float* __restrict__ x, _Float16* __restrict__ a,
              float* __restrict__ rowsum)
{
    __shared__ float lds[IN_DIM];
    __shared__ float wsum[4];
    const int tid = threadIdx.x;
    const size_t row = blockIdx.x;
    const float* xr = x + row * IN_DIM;

    #pragma unroll
    for (int v = 0; v < 4; ++v) {
        const int idx = v * 1024 + tid * 4;
        *(float4*)&lds[idx] = *(const float4*)&xr[idx];
    }
    __syncthreads();

    // 7 butterfly stages within each 128-element block (Sylvester H, symmetric)
    #pragma unroll
    for (int s = 0; s < 7; ++s) {
        const int stride = 1 << s;
        #pragma unroll
        for (int t = 0; t < 8; ++t) {
            const int p   = t * 256 + tid;          // pair index 0..2047
            const int blk = p >> 6;                 // which 128-block (64 pairs each)
            const int q   = p & 63;
            const int i   = ((q & ~(stride - 1)) << 1) | (q & (stride - 1));
            const int lo  = blk * 128 + i;
            const float u  = lds[lo];
            const float v2 = lds[lo + stride];
            lds[lo]          = u + v2;
            lds[lo + stride] = u - v2;
        }
        __syncthreads();
    }

    float ssum = 0.f;
    _Float16* ar = a + row * IN_DIM;
    #pragma unroll
    for (int v = 0; v < 4; ++v) {
        const int idx = v * 1024 + tid * 4;
        const float4 f = *(const float4*)&lds[idx];
        const float e0 = f.x * HAD_SCALE_F, e1 = f.y * HAD_SCALE_F;
        const float e2 = f.z * HAD_SCALE_F, e3 = f.w * HAD_SCALE_F;
        ssum += (e0 + e1) + (e2 + e3);
        f16x4 h = { (_Float16)e0, (_Float16)e1, (_Float16)e2, (_Float16)e3 };
        *(f16x4*)&ar[idx] = h;
    }

    // block reduction of the (scaled) row sum, f32
    #pragma unroll
    for (int off = 32; off > 0; off >>= 1) ssum += __shfl_down(ssum, off, 64);
    if ((tid & 63) == 0) wsum[tid >> 6] = ssum;
    __syncthreads();
    if (tid == 0) rowsum[row] = (wsum[0] + wsum[1]) + (wsum[2] + wsum[3]);
}

// ---------------------------------------------------------------------------
// Kernel B: unpack int4 nibbles -> fp16 weight matrix [OUT][IN] row-major.
// Each thread: one int4 (4 packed int32) -> 8 fp16 (16 B store).
// ---------------------------------------------------------------------------
__global__ __launch_bounds__(256)
void unpack_w(const int* __restrict__ wp, _Float16* __restrict__ wf)
{
    const size_t idx = (size_t)blockIdx.x * 256 + threadIdx.x;
    const int4 p = ((const int4*)wp)[idx];
    f16x8 o;
    o[0] = (_Float16)(p.x & 15);  o[1] = (_Float16)((p.x >> 4) & 15);
    o[2] = (_Float16)(p.y & 15);  o[3] = (_Float16)((p.y >> 4) & 15);
    o[4] = (_Float16)(p.z & 15);  o[5] = (_Float16)((p.z >> 4) & 15);
    o[6] = (_Float16)(p.w & 15);  o[7] = (_Float16)((p.w >> 4) & 15);
    *(f16x8*)&wf[idx * 8] = o;
}

// ---------------------------------------------------------------------------
// Kernel C: NT GEMM  y[m,n] = scale[n]*sum_k A[m,k]*W[n,k]
//                            + add[n]*rowsum[m] + bias[n]
// 128x128 tile, BK=32, 4 waves (2x2, 64x64 each), mfma_f32_16x16x32_f16,
// global_load_lds width-16 staging (m97 structure).
// ---------------------------------------------------------------------------
#define BM 128
#define BN 128
#define BK 32

__global__ __launch_bounds__(256)
void gemm_had4(const _Float16* __restrict__ A, const _Float16* __restrict__ Bw,
               const float* __restrict__ wscale, const float* __restrict__ wadd,
               const float* __restrict__ bias, const float* __restrict__ rowsum,
               float* __restrict__ out)
{
    __shared__ _Float16 As[BM * BK];
    __shared__ _Float16 Bs[BN * BK];
    const int tid  = threadIdx.x;
    const int lane = tid & 63;
    const int wv   = tid >> 6;
    const int wm   = wv >> 1;
    const int wn   = wv & 1;
    const int m0   = blockIdx.y * BM;
    const int n0   = blockIdx.x * BN;

    // staging: each global_load_lds covers 16 rows x 32 halves (1024 B).
    // global source is per-lane: row = base + lane/4, col = (lane&3)*8 halves.
    const int srow = wv * 32 + (lane >> 2);
    const int scol = (lane & 3) * 8;
    const _Float16* ag = A  + (size_t)(m0 + srow) * IN_DIM + scol;
    const _Float16* bg = Bw + (size_t)(n0 + srow) * IN_DIM + scol;
    _Float16* asB0 = &As[(wv * 32) * BK];
    _Float16* asB1 = &As[(wv * 32 + 16) * BK];
    _Float16* bsB0 = &Bs[(wv * 32) * BK];
    _Float16* bsB1 = &Bs[(wv * 32 + 16) * BK];

    f32x4 acc[4][4] = {};
    const int fr = lane & 15;          // fragment row/col
    const int kk = (lane >> 4) * 8;    // k offset within BK

    for (int k0 = 0; k0 < IN_DIM; k0 += BK) {
        __builtin_amdgcn_global_load_lds(
            (const __attribute__((address_space(1))) void*)(ag + k0),
            (__attribute__((address_space(3))) void*)asB0, 16, 0, 0);
        __builtin_amdgcn_global_load_lds(
            (const __attribute__((address_space(1))) void*)(ag + 16 * IN_DIM + k0),
            (__attribute__((address_space(3))) void*)asB1, 16, 0, 0);
        __builtin_amdgcn_global_load_lds(
            (const __attribute__((address_space(1))) void*)(bg + k0),
            (__attribute__((address_space(3))) void*)bsB0, 16, 0, 0);
        __builtin_amdgcn_global_load_lds(
            (const __attribute__((address_space(1))) void*)(bg + 16 * IN_DIM + k0),
            (__attribute__((address_space(3))) void*)bsB1, 16, 0, 0);
        __syncthreads();

        f16x8 af[4], bf[4];
        #pragma unroll
        for (int mi = 0; mi < 4; ++mi)
            af[mi] = *(const f16x8*)&As[(wm * 64 + mi * 16 + fr) * BK + kk];
        #pragma unroll
        for (int ni = 0; ni < 4; ++ni)
            bf[ni] = *(const f16x8*)&Bs[(wn * 64 + ni * 16 + fr) * BK + kk];

        #pragma unroll
        for (int mi = 0; mi < 4; ++mi)
            #pragma unroll
            for (int ni = 0; ni < 4; ++ni)
                acc[mi][ni] = __builtin_amdgcn_mfma_f32_16x16x32_f16(
                    af[mi], bf[ni], acc[mi][ni], 0, 0, 0);
        __syncthreads();
    }

    // epilogue: per-out-channel dequant + rowsum*add + bias
    #pragma unroll
    for (int ni = 0; ni < 4; ++ni) {
        const int n = n0 + wn * 64 + ni * 16 + fr;
        const float sc = wscale[n];
        const float ad = wadd[n];
        const float bi = bias[n];
        #pragma unroll
        for (int mi = 0; mi < 4; ++mi) {
            const int mb = m0 + wm * 64 + mi * 16 + (lane >> 4) * 4;
            #pragma unroll
            for (int j = 0; j < 4; ++j) {
                const int m = mb + j;
                out[(size_t)m * OUT_DIM + n] = acc[mi][ni][j] * sc + ad * rowsum[m] + bi;
            }
        }
    }
}

// ---------------------------------------------------------------------------
extern "C" void kernel_launch(void* const* d_in, const int* in_sizes, int n_in,
                              void* d_out, int out_size, void* d_ws, size_t ws_size,
                              hipStream_t stream)
{
    const float* x      = (const float*)d_in[0];
    const int*   wp     = (const int*)d_in[1];
    const float* wscale = (const float*)d_in[2];
    const float* wadd   = (const float*)d_in[3];
    const float* bias   = (const float*)d_in[4];
    float*       out    = (float*)d_out;

    const int M = in_sizes[0] / IN_DIM;   // 8192

    // workspace layout: [ wf fp16 N*K | af fp16 M*K | rowsum f32 M ]
    char* ws = (char*)d_ws;
    _Float16* wf = (_Float16*)ws;
    const size_t wf_bytes = (size_t)OUT_DIM * IN_DIM * sizeof(_Float16);
    _Float16* af = (_Float16*)(ws + wf_bytes);
    const size_t af_bytes = (size_t)M * IN_DIM * sizeof(_Float16);
    float* rowsum = (float*)(ws + wf_bytes + af_bytes);

    // B: unpack weights (N*K/2 int32, 4 per thread)
    const int unpack_threads = OUT_DIM * (IN_DIM / 2) / 4;
    unpack_w<<<unpack_threads / 256, 256, 0, stream>>>(wp, wf);

    // A: Hadamard + rowsum + fp16 convert
    had_rows<<<M, 256, 0, stream>>>(x, af, rowsum);

    // C: GEMM + epilogue
    gemm_had4<<<dim3(OUT_DIM / BN, M / BM), 256, 0, stream>>>(
        af, wf, wscale, wadd, bias, rowsum, out);
}

// Round 2
// 288.312 us; speedup vs baseline: 1.3929x; 1.3929x over previous
//
#include <hip/hip_runtime.h>
#include <hip/hip_bf16.h>
#include <hip/hip_fp16.h>

#define IN_DIM 4096
#define OUT_DIM 4096
#define HAD_SCALE_F 0.08838834764831845f   // 2^-3.5

typedef _Float16 f16x4 __attribute__((ext_vector_type(4)));
typedef _Float16 f16x8 __attribute__((ext_vector_type(8)));
typedef float    f32x4 __attribute__((ext_vector_type(4)));

// ---------------------------------------------------------------------------
// Kernel A: per-row blockwise Hadamard (FWHT over 128-blocks), scale, f32
// rowsum, convert to fp16. One block (256 thr) per row of 4096 floats.
// ---------------------------------------------------------------------------
__global__ __launch_bounds__(256)
void had_rows(const float* __restrict__ x, _Float16* __restrict__ a,
              float* __restrict__ rowsum)
{
    __shared__ float lds[IN_DIM];
    __shared__ float wsum[4];
    const int tid = threadIdx.x;
    const size_t row = blockIdx.x;
    const float* xr = x + row * IN_DIM;

    #pragma unroll
    for (int v = 0; v < 4; ++v) {
        const int idx = v * 1024 + tid * 4;
        *(float4*)&lds[idx] = *(const float4*)&xr[idx];
    }
    __syncthreads();

    #pragma unroll
    for (int s = 0; s < 7; ++s) {
        const int stride = 1 << s;
        #pragma unroll
        for (int t = 0; t < 8; ++t) {
            const int p   = t * 256 + tid;
            const int blk = p >> 6;
            const int q   = p & 63;
            const int i   = ((q & ~(stride - 1)) << 1) | (q & (stride - 1));
            const int lo  = blk * 128 + i;
            const float u  = lds[lo];
            const float v2 = lds[lo + stride];
            lds[lo]          = u + v2;
            lds[lo + stride] = u - v2;
        }
        __syncthreads();
    }

    float ssum = 0.f;
    _Float16* ar = a + row * IN_DIM;
    #pragma unroll
    for (int v = 0; v < 4; ++v) {
        const int idx = v * 1024 + tid * 4;
        const float4 f = *(const float4*)&lds[idx];
        const float e0 = f.x * HAD_SCALE_F, e1 = f.y * HAD_SCALE_F;
        const float e2 = f.z * HAD_SCALE_F, e3 = f.w * HAD_SCALE_F;
        ssum += (e0 + e1) + (e2 + e3);
        f16x4 h = { (_Float16)e0, (_Float16)e1, (_Float16)e2, (_Float16)e3 };
        *(f16x4*)&ar[idx] = h;
    }

    #pragma unroll
    for (int off = 32; off > 0; off >>= 1) ssum += __shfl_down(ssum, off, 64);
    if ((tid & 63) == 0) wsum[tid >> 6] = ssum;
    __syncthreads();
    if (tid == 0) rowsum[row] = (wsum[0] + wsum[1]) + (wsum[2] + wsum[3]);
}

// ---------------------------------------------------------------------------
// Kernel B: unpack int4 nibbles -> fp16 weight matrix [OUT][IN] row-major.
// ---------------------------------------------------------------------------
__global__ __launch_bounds__(256)
void unpack_w(const int* __restrict__ wp, _Float16* __restrict__ wf)
{
    const size_t idx = (size_t)blockIdx.x * 256 + threadIdx.x;
    const int4 p = ((const int4*)wp)[idx];
    f16x8 o;
    o[0] = (_Float16)(p.x & 15);  o[1] = (_Float16)((p.x >> 4) & 15);
    o[2] = (_Float16)(p.y & 15);  o[3] = (_Float16)((p.y >> 4) & 15);
    o[4] = (_Float16)(p.z & 15);  o[5] = (_Float16)((p.z >> 4) & 15);
    o[6] = (_Float16)(p.w & 15);  o[7] = (_Float16)((p.w >> 4) & 15);
    *(f16x8*)&wf[idx * 8] = o;
}

// ---------------------------------------------------------------------------
// Kernel C: 256x256 8-phase GEMM (m201 template ported to fp16).
//   y[m,n] = wscale[n]*sum_k A[m,k]*W[n,k] + wadd[n]*rowsum[m] + bias[n]
// 512 thr = 8 waves (2M x 4N), each wave 128x64 out. BK=64, double-buffered
// 128 KiB LDS. 16 mfma/phase, 2 global_load_lds/phase, vmcnt(6) at P4/P8.
// LDS swizzle: chunk (row,c) stored at slot c^(row&7); applied on the stage
// SOURCE address (LDS dest stays linear for global_load_lds) and on ds_read.
// ---------------------------------------------------------------------------
#define NT (IN_DIM / 64)    // 64 K-tiles of 64
#define NI (NT / 2)         // 32 iterations, 2 K-tiles each

#define BAR()        asm volatile("s_barrier" ::: "memory")
#define WAIT_LGKM0() asm volatile("s_waitcnt lgkmcnt(0)" ::: "memory")
#define WAIT_VM(N)   asm volatile("s_waitcnt vmcnt(" #N ")" ::: "memory")

// LDS layout: A0 @ 0, B0 @ 32768, A1 @ 65536, B1 @ 98304 (each 32 KiB)
#define STAGE_A(p, R, kt) __builtin_amdgcn_global_load_lds( \
    (const __attribute__((address_space(1))) void*)(sA + (((size_t)(R)) << 18) + ((kt) << 6)), \
    (__attribute__((address_space(3))) void*)(smem + (p) * 65536 + (R) * 8192 + dstA), 16, 0, 0)
#define STAGE_B(p, R, kt) __builtin_amdgcn_global_load_lds( \
    (const __attribute__((address_space(1))) void*)(sB + (((size_t)(R)) << 18) + ((kt) << 6)), \
    (__attribute__((address_space(3))) void*)(smem + (p) * 65536 + (R) * 8192 + dstB), 16, 0, 0)

#define LDA(p, mq, mi, kb) (*(const f16x8*)(smem + (p)*65536 + (mq)*8192 + (mi)*2048 + aOffK[kb]))
#define LDB(p, nq, ni, kb) (*(const f16x8*)(smem + (p)*65536 + (nq)*4096 + (ni)*2048 + bOffK[kb]))

#define LOAD_A(p, mq) do { \
    _Pragma("unroll") for (int mi = 0; mi < 4; ++mi) { \
        afr[mi][0] = LDA(p, mq, mi, 0); \
        afr[mi][1] = LDA(p, mq, mi, 1); \
    } } while (0)

#define LOAD_B(p, nq) do { \
    _Pragma("unroll") for (int ni = 0; ni < 2; ++ni) { \
        bfr[(nq)*2+ni][0] = LDB(p, nq, ni, 0); \
        bfr[(nq)*2+ni][1] = LDB(p, nq, ni, 1); \
    } } while (0)

#define MFMA_QUAD(mq, nq) do { \
    __builtin_amdgcn_s_setprio(1); \
    _Pragma("unroll") for (int mi = 0; mi < 4; ++mi) \
    _Pragma("unroll") for (int ni = 0; ni < 2; ++ni) \
    _Pragma("unroll") for (int kb = 0; kb < 2; ++kb) \
        acc[(mq)*4+mi][(nq)*2+ni] = __builtin_amdgcn_mfma_f32_16x16x32_f16( \
            afr[mi][kb], bfr[(nq)*2+ni][kb], acc[(mq)*4+mi][(nq)*2+ni], 0, 0, 0); \
    __builtin_amdgcn_s_setprio(0); \
} while (0)

__global__ __launch_bounds__(512, 2)
void gemm8p(const _Float16* __restrict__ A, const _Float16* __restrict__ Bw,
            const float* __restrict__ wscale, const float* __restrict__ wadd,
            const float* __restrict__ bias, const float* __restrict__ rowsum,
            float* __restrict__ out)
{
    __shared__ char smem[131072];

    const int tid  = threadIdx.x;
    const int lane = tid & 63;
    const int w    = tid >> 6;     // wave 0..7
    const int wm   = w >> 2;       // 0..1
    const int wn   = w & 3;        // 0..3

    // XCD-aware bijective swizzle: 512 wgs, 8 XCDs, 64 per XCD
    const int bid = blockIdx.x;
    const int wg  = (bid & 7) * 64 + (bid >> 3);
    const int m0  = (wg >> 4) * 256;   // M/256 = 32
    const int n0  = (wg & 15) * 256;   // N/256 = 16

    // ---- staging addresses (pre-swizzled source, linear LDS dest) ----
    // thread t covers chunk q = R*512 + t; LDS slot q&7 holds logical
    // chunk column c = (q&7) ^ ((q>>3)&7) of row q>>3.
    const int rt = tid >> 3;
    const int ct = (tid & 7) ^ (rt & 7);
    const _Float16* sA = A  + (size_t)(m0 + rt) * IN_DIM + ct * 8;
    const _Float16* sB = Bw + (size_t)(n0 + rt) * IN_DIM + ct * 8;
    const int dstA = w * 1024;
    const int dstB = 32768 + w * 1024;

    // ---- fragment read offsets (swizzled) ----
    const int l15 = lane & 15, g = lane >> 4, l7 = lane & 7;
    const int s0 = (g ^ l7) << 4;            // slot byte for kb=0
    int aOffK[2], bOffK[2];
    aOffK[0] = (wm * 128 + l15) * 128 + s0;
    aOffK[1] = (wm * 128 + l15) * 128 + (s0 ^ 64);
    bOffK[0] = 32768 + (wn * 64 + l15) * 128 + s0;
    bOffK[1] = 32768 + (wn * 64 + l15) * 128 + (s0 ^ 64);

    f16x8 afr[4][2], bfr[4][2];
    f32x4 acc[8][4] = {};

    // ---- prologue: kt0 -> buf0, kt1 -> buf1 ----
    #pragma unroll
    for (int R = 0; R < 4; ++R) { STAGE_A(0, R, 0); STAGE_B(0, R, 0); }
    #pragma unroll
    for (int R = 0; R < 4; ++R) { STAGE_A(1, R, 1); STAGE_B(1, R, 1); }
    WAIT_VM(8);     // buf0 landed (buf1's 8 still in flight)
    BAR();

    #pragma unroll 1
    for (int it = 0; it < NI; ++it) {
        const int kt1 = 2 * it + 1;
        const int kt2 = (2 * it + 2) & (NT - 1);  // wraps harmlessly at tail
        const int kt3 = (2 * it + 3) & (NT - 1);

        // P1: quad(0,0) of buf0 | stage buf1.B rounds 2,3 (kt1)
        LOAD_A(0, 0); LOAD_B(0, 0);
        if (it) { STAGE_B(1, 2, kt1); STAGE_B(1, 3, kt1); }
        BAR(); WAIT_LGKM0();
        MFMA_QUAD(0, 0);
        BAR();

        // P2: quad(0,1) | stage buf0.A rounds 0,2 (kt2)
        LOAD_B(0, 1);
        STAGE_A(0, 0, kt2); STAGE_A(0, 2, kt2);
        BAR(); WAIT_LGKM0();
        MFMA_QUAD(0, 1);
        BAR();

        // P3: quad(1,0) | stage buf0.B rounds 0,1 (kt2)
        LOAD_A(0, 1);
        STAGE_B(0, 0, kt2); STAGE_B(0, 1, kt2);
        BAR(); WAIT_LGKM0();
        MFMA_QUAD(1, 0);
        BAR();

        // P4: quad(1,1) | stage buf0.A rounds 1,3 (kt2) | vmcnt(6)
        STAGE_A(0, 1, kt2); STAGE_A(0, 3, kt2);
        BAR(); WAIT_LGKM0();
        MFMA_QUAD(1, 1);
        WAIT_VM(6);
        BAR();

        // P5: quad(0,0) of buf1 | stage buf0.B rounds 2,3 (kt2)
        LOAD_A(1, 0); LOAD_B(1, 0);
        STAGE_B(0, 2, kt2); STAGE_B(0, 3, kt2);
        BAR(); WAIT_LGKM0();
        MFMA_QUAD(0, 0);
        BAR();

        // P6: quad(0,1) | stage buf1.A rounds 0,2 (kt3)
        LOAD_B(1, 1);
        STAGE_A(1, 0, kt3); STAGE_A(1, 2, kt3);
        BAR(); WAIT_LGKM0();
        MFMA_QUAD(0, 1);
        BAR();

        // P7: quad(1,0) | stage buf1.B rounds 0,1 (kt3)
        LOAD_A(1, 1);
        STAGE_B(1, 0, kt3); STAGE_B(1, 1, kt3);
        BAR(); WAIT_LGKM0();
        MFMA_QUAD(1, 0);
        BAR();

        // P8: quad(1,1) | stage buf1.A rounds 1,3 (kt3) | vmcnt(6)
        STAGE_A(1, 1, kt3); STAGE_A(1, 3, kt3);
        BAR(); WAIT_LGKM0();
        MFMA_QUAD(1, 1);
        WAIT_VM(6);
        BAR();
    }

    // ---- epilogue: dequant + rowsum*add + bias ----
    #pragma unroll
    for (int n = 0; n < 4; ++n) {
        const int col = n0 + wn * 64 + n * 16 + l15;
        const float sc = wscale[col];
        const float ad = wadd[col];
        const float bi = bias[col];
        #pragma unroll
        for (int m = 0; m < 8; ++m) {
            const int row = m0 + wm * 128 + m * 16 + g * 4;
            #pragma unroll
            for (int j = 0; j < 4; ++j) {
                const float rs = rowsum[row + j];
                out[(size_t)(row + j) * OUT_DIM + col] = acc[m][n][j] * sc + ad * rs + bi;
            }
        }
    }
}

// ---------------------------------------------------------------------------
extern "C" void kernel_launch(void* const* d_in, const int* in_sizes, int n_in,
                              void* d_out, int out_size, void* d_ws, size_t ws_size,
                              hipStream_t stream)
{
    const float* x      = (const float*)d_in[0];
    const int*   wp     = (const int*)d_in[1];
    const float* wscale = (const float*)d_in[2];
    const float* wadd   = (const float*)d_in[3];
    const float* bias   = (const float*)d_in[4];
    float*       out    = (float*)d_out;

    const int M = in_sizes[0] / IN_DIM;   // 8192

    char* ws = (char*)d_ws;
    _Float16* wf = (_Float16*)ws;
    const size_t wf_bytes = (size_t)OUT_DIM * IN_DIM * sizeof(_Float16);
    _Float16* af = (_Float16*)(ws + wf_bytes);
    const size_t af_bytes = (size_t)M * IN_DIM * sizeof(_Float16);
    float* rowsum = (float*)(ws + wf_bytes + af_bytes);

    const int unpack_threads = OUT_DIM * (IN_DIM / 2) / 4;
    unpack_w<<<unpack_threads / 256, 256, 0, stream>>>(wp, wf);
    had_rows<<<M, 256, 0, stream>>>(x, af, rowsum);

    gemm8p<<<(M / 256) * (OUT_DIM / 256), 512, 0, stream>>>(
        af, wf, wscale, wadd, bias, rowsum, out);
}

// Round 3
// 285.561 us; speedup vs baseline: 1.4063x; 1.0096x over previous
//
#include <hip/hip_runtime.h>
#include <hip/hip_bf16.h>
#include <hip/hip_fp16.h>

#define IN_DIM 4096
#define OUT_DIM 4096
#define HAD_SCALE_F 0.08838834764831845f   // 2^-3.5

typedef _Float16 f16x4 __attribute__((ext_vector_type(4)));
typedef _Float16 f16x8 __attribute__((ext_vector_type(8)));
typedef float    f32x4 __attribute__((ext_vector_type(4)));

// ---------------------------------------------------------------------------
// Kernel A: per-row blockwise Hadamard (FWHT over 128-blocks), scale, f32
// rowsum, convert to fp16. One block (256 thr) per row of 4096 floats.
// ---------------------------------------------------------------------------
__global__ __launch_bounds__(256)
void had_rows(const float* __restrict__ x, _Float16* __restrict__ a,
              float* __restrict__ rowsum)
{
    __shared__ float lds[IN_DIM];
    __shared__ float wsum[4];
    const int tid = threadIdx.x;
    const size_t row = blockIdx.x;
    const float* xr = x + row * IN_DIM;

    #pragma unroll
    for (int v = 0; v < 4; ++v) {
        const int idx = v * 1024 + tid * 4;
        *(float4*)&lds[idx] = *(const float4*)&xr[idx];
    }
    __syncthreads();

    #pragma unroll
    for (int s = 0; s < 7; ++s) {
        const int stride = 1 << s;
        #pragma unroll
        for (int t = 0; t < 8; ++t) {
            const int p   = t * 256 + tid;
            const int blk = p >> 6;
            const int q   = p & 63;
            const int i   = ((q & ~(stride - 1)) << 1) | (q & (stride - 1));
            const int lo  = blk * 128 + i;
            const float u  = lds[lo];
            const float v2 = lds[lo + stride];
            lds[lo]          = u + v2;
            lds[lo + stride] = u - v2;
        }
        __syncthreads();
    }

    float ssum = 0.f;
    _Float16* ar = a + row * IN_DIM;
    #pragma unroll
    for (int v = 0; v < 4; ++v) {
        const int idx = v * 1024 + tid * 4;
        const float4 f = *(const float4*)&lds[idx];
        const float e0 = f.x * HAD_SCALE_F, e1 = f.y * HAD_SCALE_F;
        const float e2 = f.z * HAD_SCALE_F, e3 = f.w * HAD_SCALE_F;
        ssum += (e0 + e1) + (e2 + e3);
        f16x4 h = { (_Float16)e0, (_Float16)e1, (_Float16)e2, (_Float16)e3 };
        *(f16x4*)&ar[idx] = h;
    }

    #pragma unroll
    for (int off = 32; off > 0; off >>= 1) ssum += __shfl_down(ssum, off, 64);
    if ((tid & 63) == 0) wsum[tid >> 6] = ssum;
    __syncthreads();
    if (tid == 0) rowsum[row] = (wsum[0] + wsum[1]) + (wsum[2] + wsum[3]);
}

// ---------------------------------------------------------------------------
// Kernel B: unpack int4 nibbles -> fp16 weight matrix [OUT][IN] row-major.
// ---------------------------------------------------------------------------
__global__ __launch_bounds__(256)
void unpack_w(const int* __restrict__ wp, _Float16* __restrict__ wf)
{
    const size_t idx = (size_t)blockIdx.x * 256 + threadIdx.x;
    const int4 p = ((const int4*)wp)[idx];
    f16x8 o;
    o[0] = (_Float16)(p.x & 15);  o[1] = (_Float16)((p.x >> 4) & 15);
    o[2] = (_Float16)(p.y & 15);  o[3] = (_Float16)((p.y >> 4) & 15);
    o[4] = (_Float16)(p.z & 15);  o[5] = (_Float16)((p.z >> 4) & 15);
    o[6] = (_Float16)(p.w & 15);  o[7] = (_Float16)((p.w >> 4) & 15);
    *(f16x8*)&wf[idx * 8] = o;
}

// ---------------------------------------------------------------------------
// Kernel C: 256x256 8-phase GEMM.
//   y[m,n] = wscale[n]*sum_k A[m,k]*W[n,k] + wadd[n]*rowsum[m] + bias[n]
// 512 thr = 8 waves (2M x 4N), each wave 128x64 out. BK=64, double-buffered
// 128 KiB LDS. 16 mfma/phase, vmcnt(6) at P4/P8.
// Round-3 change: NO explicit lgkmcnt(0) drain — loads are ordered in MFMA
// consumption order (B first, then A) and the MFMA nest consumes
// earliest-loaded frags first, so the compiler emits a counted lgkmcnt
// ladder and the LDS pipe drains UNDER the MFMA burst.
// ---------------------------------------------------------------------------
#define NT (IN_DIM / 64)    // 64 K-tiles of 64
#define NI (NT / 2)         // 32 iterations, 2 K-tiles each

#define BAR()        asm volatile("s_barrier" ::: "memory")
#define WAIT_VM(N)   asm volatile("s_waitcnt vmcnt(" #N ")" ::: "memory")

// LDS layout: A0 @ 0, B0 @ 32768, A1 @ 65536, B1 @ 98304 (each 32 KiB)
#define STAGE_A(p, R, kt) __builtin_amdgcn_global_load_lds( \
    (const __attribute__((address_space(1))) void*)(sA + (((size_t)(R)) << 18) + ((kt) << 6)), \
    (__attribute__((address_space(3))) void*)(smem + (p) * 65536 + (R) * 8192 + dstA), 16, 0, 0)
#define STAGE_B(p, R, kt) __builtin_amdgcn_global_load_lds( \
    (const __attribute__((address_space(1))) void*)(sB + (((size_t)(R)) << 18) + ((kt) << 6)), \
    (__attribute__((address_space(3))) void*)(smem + (p) * 65536 + (R) * 8192 + dstB), 16, 0, 0)

#define LDA(p, mq, mi, kb) (*(const f16x8*)(smem + (p)*65536 + (mq)*8192 + (mi)*2048 + aOffK[kb]))
#define LDB(p, nq, ni, kb) (*(const f16x8*)(smem + (p)*65536 + (nq)*4096 + (ni)*2048 + bOffK[kb]))

#define LOAD_A(p, mq) do { \
    _Pragma("unroll") for (int mi = 0; mi < 4; ++mi) { \
        afr[mi][0] = LDA(p, mq, mi, 0); \
        afr[mi][1] = LDA(p, mq, mi, 1); \
    } } while (0)

#define LOAD_B(p, nq) do { \
    _Pragma("unroll") for (int ni = 0; ni < 2; ++ni) { \
        bfr[(nq)*2+ni][0] = LDB(p, nq, ni, 0); \
        bfr[(nq)*2+ni][1] = LDB(p, nq, ni, 1); \
    } } while (0)

// A-frags freshly loaded (consume mi-ascending = load order)
#define MFMA_QUAD_MI(mq, nq) do { \
    __builtin_amdgcn_s_setprio(1); \
    _Pragma("unroll") for (int mi = 0; mi < 4; ++mi) \
    _Pragma("unroll") for (int ni = 0; ni < 2; ++ni) \
    _Pragma("unroll") for (int kb = 0; kb < 2; ++kb) \
        acc[(mq)*4+mi][(nq)*2+ni] = __builtin_amdgcn_mfma_f32_16x16x32_f16( \
            afr[mi][kb], bfr[(nq)*2+ni][kb], acc[(mq)*4+mi][(nq)*2+ni], 0, 0, 0); \
    __builtin_amdgcn_s_setprio(0); \
} while (0)

// B-frags freshly loaded (consume ni-ascending = load order)
#define MFMA_QUAD_NI(mq, nq) do { \
    __builtin_amdgcn_s_setprio(1); \
    _Pragma("unroll") for (int ni = 0; ni < 2; ++ni) \
    _Pragma("unroll") for (int mi = 0; mi < 4; ++mi) \
    _Pragma("unroll") for (int kb = 0; kb < 2; ++kb) \
        acc[(mq)*4+mi][(nq)*2+ni] = __builtin_amdgcn_mfma_f32_16x16x32_f16( \
            afr[mi][kb], bfr[(nq)*2+ni][kb], acc[(mq)*4+mi][(nq)*2+ni], 0, 0, 0); \
    __builtin_amdgcn_s_setprio(0); \
} while (0)

__global__ __launch_bounds__(512, 2)
void gemm8p(const _Float16* __restrict__ A, const _Float16* __restrict__ Bw,
            const float* __restrict__ wscale, const float* __restrict__ wadd,
            const float* __restrict__ bias, const float* __restrict__ rowsum,
            float* __restrict__ out)
{
    __shared__ char smem[131072];

    const int tid  = threadIdx.x;
    const int lane = tid & 63;
    const int w    = tid >> 6;     // wave 0..7
    const int wm   = w >> 2;       // 0..1
    const int wn   = w & 3;        // 0..3

    // XCD-aware bijective swizzle: 512 wgs, 8 XCDs, 64 per XCD
    const int bid = blockIdx.x;
    const int wg  = (bid & 7) * 64 + (bid >> 3);
    const int m0  = (wg >> 4) * 256;   // M/256 = 32
    const int n0  = (wg & 15) * 256;   // N/256 = 16

    // ---- staging addresses (pre-swizzled source, linear LDS dest) ----
    const int rt = tid >> 3;
    const int ct = (tid & 7) ^ (rt & 7);
    const _Float16* sA = A  + (size_t)(m0 + rt) * IN_DIM + ct * 8;
    const _Float16* sB = Bw + (size_t)(n0 + rt) * IN_DIM + ct * 8;
    const int dstA = w * 1024;
    const int dstB = 32768 + w * 1024;

    // ---- fragment read offsets (swizzled) ----
    const int l15 = lane & 15, g = lane >> 4, l7 = lane & 7;
    const int s0 = (g ^ l7) << 4;            // slot byte for kb=0
    int aOffK[2], bOffK[2];
    aOffK[0] = (wm * 128 + l15) * 128 + s0;
    aOffK[1] = (wm * 128 + l15) * 128 + (s0 ^ 64);
    bOffK[0] = 32768 + (wn * 64 + l15) * 128 + s0;
    bOffK[1] = 32768 + (wn * 64 + l15) * 128 + (s0 ^ 64);

    f16x8 afr[4][2], bfr[4][2];
    f32x4 acc[8][4] = {};

    // ---- prologue: kt0 -> buf0, kt1 -> buf1 ----
    #pragma unroll
    for (int R = 0; R < 4; ++R) { STAGE_A(0, R, 0); STAGE_B(0, R, 0); }
    #pragma unroll
    for (int R = 0; R < 4; ++R) { STAGE_A(1, R, 1); STAGE_B(1, R, 1); }
    WAIT_VM(8);     // buf0 landed (buf1's 8 still in flight)
    BAR();

    #pragma unroll 1
    for (int it = 0; it < NI; ++it) {
        const int kt1 = 2 * it + 1;
        const int kt2 = (2 * it + 2) & (NT - 1);  // wraps harmlessly at tail
        const int kt3 = (2 * it + 3) & (NT - 1);

        // P1: quad(0,0) of buf0 | stage buf1.B rounds 2,3 (kt1)
        LOAD_B(0, 0); LOAD_A(0, 0);
        if (it) { STAGE_B(1, 2, kt1); STAGE_B(1, 3, kt1); }
        BAR();
        MFMA_QUAD_MI(0, 0);
        BAR();

        // P2: quad(0,1) | stage buf0.A rounds 0,2 (kt2)
        LOAD_B(0, 1);
        STAGE_A(0, 0, kt2); STAGE_A(0, 2, kt2);
        BAR();
        MFMA_QUAD_NI(0, 1);
        BAR();

        // P3: quad(1,0) | stage buf0.B rounds 0,1 (kt2)
        LOAD_A(0, 1);
        STAGE_B(0, 0, kt2); STAGE_B(0, 1, kt2);
        BAR();
        MFMA_QUAD_MI(1, 0);
        BAR();

        // P4: quad(1,1) | stage buf0.A rounds 1,3 (kt2) | vmcnt(6)
        STAGE_A(0, 1, kt2); STAGE_A(0, 3, kt2);
        BAR();
        MFMA_QUAD_MI(1, 1);
        WAIT_VM(6);
        BAR();

        // P5: quad(0,0) of buf1 | stage buf0.B rounds 2,3 (kt2)
        LOAD_B(1, 0); LOAD_A(1, 0);
        STAGE_B(0, 2, kt2); STAGE_B(0, 3, kt2);
        BAR();
        MFMA_QUAD_MI(0, 0);
        BAR();

        // P6: quad(0,1) | stage buf1.A rounds 0,2 (kt3)
        LOAD_B(1, 1);
        STAGE_A(1, 0, kt3); STAGE_A(1, 2, kt3);
        BAR();
        MFMA_QUAD_NI(0, 1);
        BAR();

        // P7: quad(1,0) | stage buf1.B rounds 0,1 (kt3)
        LOAD_A(1, 1);
        STAGE_B(1, 0, kt3); STAGE_B(1, 1, kt3);
        BAR();
        MFMA_QUAD_MI(1, 0);
        BAR();

        // P8: quad(1,1) | stage buf1.A rounds 1,3 (kt3) | vmcnt(6)
        STAGE_A(1, 1, kt3); STAGE_A(1, 3, kt3);
        BAR();
        MFMA_QUAD_MI(1, 1);
        WAIT_VM(6);
        BAR();
    }

    // ---- epilogue: dequant + rowsum*add + bias ----
    #pragma unroll
    for (int n = 0; n < 4; ++n) {
        const int col = n0 + wn * 64 + n * 16 + l15;
        const float sc = wscale[col];
        const float ad = wadd[col];
        const float bi = bias[col];
        #pragma unroll
        for (int m = 0; m < 8; ++m) {
            const int row = m0 + wm * 128 + m * 16 + g * 4;
            const float4 rs4 = *(const float4*)&rowsum[row];
            #pragma unroll
            for (int j = 0; j < 4; ++j) {
                const float rs = (j == 0) ? rs4.x : (j == 1) ? rs4.y : (j == 2) ? rs4.z : rs4.w;
                out[(size_t)(row + j) * OUT_DIM + col] = acc[m][n][j] * sc + ad * rs + bi;
            }
        }
    }
}

// ---------------------------------------------------------------------------
extern "C" void kernel_launch(void* const* d_in, const int* in_sizes, int n_in,
                              void* d_out, int out_size, void* d_ws, size_t ws_size,
                              hipStream_t stream)
{
    const float* x      = (const float*)d_in[0];
    const int*   wp     = (const int*)d_in[1];
    const float* wscale = (const float*)d_in[2];
    const float* wadd   = (const float*)d_in[3];
    const float* bias   = (const float*)d_in[4];
    float*       out    = (float*)d_out;

    const int M = in_sizes[0] / IN_DIM;   // 8192

    char* ws = (char*)d_ws;
    _Float16* wf = (_Float16*)ws;
    const size_t wf_bytes = (size_t)OUT_DIM * IN_DIM * sizeof(_Float16);
    _Float16* af = (_Float16*)(ws + wf_bytes);
    const size_t af_bytes = (size_t)M * IN_DIM * sizeof(_Float16);
    float* rowsum = (float*)(ws + wf_bytes + af_bytes);

    const int unpack_threads = OUT_DIM * (IN_DIM / 2) / 4;
    unpack_w<<<unpack_threads / 256, 256, 0, stream>>>(wp, wf);
    had_rows<<<M, 256, 0, stream>>>(x, af, rowsum);

    gemm8p<<<(M / 256) * (OUT_DIM / 256), 512, 0, stream>>>(
        af, wf, wscale, wadd, bias, rowsum, out);
}

// Round 4
// 280.170 us; speedup vs baseline: 1.4334x; 1.0192x over previous
//
#include <hip/hip_runtime.h>
#include <hip/hip_bf16.h>
#include <hip/hip_fp16.h>

#define IN_DIM 4096
#define OUT_DIM 4096
#define HAD_SCALE_F 0.08838834764831845f   // 2^-3.5

typedef _Float16 f16x4 __attribute__((ext_vector_type(4)));
typedef _Float16 f16x8 __attribute__((ext_vector_type(8)));
typedef float    f32x4 __attribute__((ext_vector_type(4)));

// ---------------------------------------------------------------------------
// Kernel A: per-row blockwise Hadamard (FWHT over 128-blocks), scale, f32
// rowsum, convert to fp16. One block (256 thr) per row of 4096 floats.
// ---------------------------------------------------------------------------
__global__ __launch_bounds__(256)
void had_rows(const float* __restrict__ x, _Float16* __restrict__ a,
              float* __restrict__ rowsum)
{
    __shared__ float lds[IN_DIM];
    __shared__ float wsum[4];
    const int tid = threadIdx.x;
    const size_t row = blockIdx.x;
    const float* xr = x + row * IN_DIM;

    #pragma unroll
    for (int v = 0; v < 4; ++v) {
        const int idx = v * 1024 + tid * 4;
        *(float4*)&lds[idx] = *(const float4*)&xr[idx];
    }
    __syncthreads();

    #pragma unroll
    for (int s = 0; s < 7; ++s) {
        const int stride = 1 << s;
        #pragma unroll
        for (int t = 0; t < 8; ++t) {
            const int p   = t * 256 + tid;
            const int blk = p >> 6;
            const int q   = p & 63;
            const int i   = ((q & ~(stride - 1)) << 1) | (q & (stride - 1));
            const int lo  = blk * 128 + i;
            const float u  = lds[lo];
            const float v2 = lds[lo + stride];
            lds[lo]          = u + v2;
            lds[lo + stride] = u - v2;
        }
        __syncthreads();
    }

    float ssum = 0.f;
    _Float16* ar = a + row * IN_DIM;
    #pragma unroll
    for (int v = 0; v < 4; ++v) {
        const int idx = v * 1024 + tid * 4;
        const float4 f = *(const float4*)&lds[idx];
        const float e0 = f.x * HAD_SCALE_F, e1 = f.y * HAD_SCALE_F;
        const float e2 = f.z * HAD_SCALE_F, e3 = f.w * HAD_SCALE_F;
        ssum += (e0 + e1) + (e2 + e3);
        f16x4 h = { (_Float16)e0, (_Float16)e1, (_Float16)e2, (_Float16)e3 };
        *(f16x4*)&ar[idx] = h;
    }

    #pragma unroll
    for (int off = 32; off > 0; off >>= 1) ssum += __shfl_down(ssum, off, 64);
    if ((tid & 63) == 0) wsum[tid >> 6] = ssum;
    __syncthreads();
    if (tid == 0) rowsum[row] = (wsum[0] + wsum[1]) + (wsum[2] + wsum[3]);
}

// ---------------------------------------------------------------------------
// Kernel B: unpack int4 nibbles -> fp16 weight matrix [OUT][IN] row-major.
// ---------------------------------------------------------------------------
__global__ __launch_bounds__(256)
void unpack_w(const int* __restrict__ wp, _Float16* __restrict__ wf)
{
    const size_t idx = (size_t)blockIdx.x * 256 + threadIdx.x;
    const int4 p = ((const int4*)wp)[idx];
    f16x8 o;
    o[0] = (_Float16)(p.x & 15);  o[1] = (_Float16)((p.x >> 4) & 15);
    o[2] = (_Float16)(p.y & 15);  o[3] = (_Float16)((p.y >> 4) & 15);
    o[4] = (_Float16)(p.z & 15);  o[5] = (_Float16)((p.z >> 4) & 15);
    o[6] = (_Float16)(p.w & 15);  o[7] = (_Float16)((p.w >> 4) & 15);
    *(f16x8*)&wf[idx * 8] = o;
}

// ---------------------------------------------------------------------------
// Kernel C: 256x256 8-phase GEMM, register-pipelined.
//   y[m,n] = wscale[n]*sum_k A[m,k]*W[n,k] + wadd[n]*rowsum[m] + bias[n]
// Round-4 change: ds_reads issued ONE PHASE AHEAD of their consuming MFMA
// (A-frags double-buffered afrA/afrB; B-frags have a 2-phase reuse gap so a
// single set suffices). One barrier per phase (R/W ledger: every LDS region's
// last reader is >=2 phases before its re-staging; same-phase read/stage
// regions disjoint). vmcnt(4) at START of P4/P8 (drains exactly the stages
// the upcoming reads need, issued >=3 phases earlier).
// ---------------------------------------------------------------------------
#define NT (IN_DIM / 64)    // 64 K-tiles of 64
#define NI (NT / 2)         // 32 iterations, 2 K-tiles each

#define BAR()        asm volatile("s_barrier" ::: "memory")
#define WAIT_VM(N)   asm volatile("s_waitcnt vmcnt(" #N ")" ::: "memory")

// LDS layout: A0 @ 0, B0 @ 32768, A1 @ 65536, B1 @ 98304 (each 32 KiB)
#define STAGE_A(p, R, kt) __builtin_amdgcn_global_load_lds( \
    (const __attribute__((address_space(1))) void*)(sA + (((size_t)(R)) << 18) + ((kt) << 6)), \
    (__attribute__((address_space(3))) void*)(smem + (p) * 65536 + (R) * 8192 + dstA), 16, 0, 0)
#define STAGE_B(p, R, kt) __builtin_amdgcn_global_load_lds( \
    (const __attribute__((address_space(1))) void*)(sB + (((size_t)(R)) << 18) + ((kt) << 6)), \
    (__attribute__((address_space(3))) void*)(smem + (p) * 65536 + (R) * 8192 + dstB), 16, 0, 0)

#define LDA(p, mq, mi, kb) (*(const f16x8*)(smem + (p)*65536 + (mq)*8192 + (mi)*2048 + aOffK[kb]))
#define LDB(p, nq, ni, kb) (*(const f16x8*)(smem + (p)*65536 + (nq)*4096 + (ni)*2048 + bOffK[kb]))

#define LOAD_A_TO(dst, p, mq) do { \
    _Pragma("unroll") for (int mi = 0; mi < 4; ++mi) { \
        dst[mi][0] = LDA(p, mq, mi, 0); \
        dst[mi][1] = LDA(p, mq, mi, 1); \
    } } while (0)

#define LOAD_B(p, nq) do { \
    _Pragma("unroll") for (int ni = 0; ni < 2; ++ni) { \
        bfr[(nq)*2+ni][0] = LDB(p, nq, ni, 0); \
        bfr[(nq)*2+ni][1] = LDB(p, nq, ni, 1); \
    } } while (0)

#define MFMA_Q(abuf, mq, nq) do { \
    __builtin_amdgcn_s_setprio(1); \
    _Pragma("unroll") for (int mi = 0; mi < 4; ++mi) \
    _Pragma("unroll") for (int ni = 0; ni < 2; ++ni) \
    _Pragma("unroll") for (int kb = 0; kb < 2; ++kb) \
        acc[(mq)*4+mi][(nq)*2+ni] = __builtin_amdgcn_mfma_f32_16x16x32_f16( \
            abuf[mi][kb], bfr[(nq)*2+ni][kb], acc[(mq)*4+mi][(nq)*2+ni], 0, 0, 0); \
    __builtin_amdgcn_s_setprio(0); \
} while (0)

__global__ __launch_bounds__(512, 2)
void gemm8p(const _Float16* __restrict__ A, const _Float16* __restrict__ Bw,
            const float* __restrict__ wscale, const float* __restrict__ wadd,
            const float* __restrict__ bias, const float* __restrict__ rowsum,
            float* __restrict__ out)
{
    __shared__ char smem[131072];

    const int tid  = threadIdx.x;
    const int lane = tid & 63;
    const int w    = tid >> 6;     // wave 0..7
    const int wm   = w >> 2;       // 0..1
    const int wn   = w & 3;        // 0..3

    // XCD-aware bijective swizzle: 512 wgs, 8 XCDs, 64 per XCD
    const int bid = blockIdx.x;
    const int wg  = (bid & 7) * 64 + (bid >> 3);
    const int m0  = (wg >> 4) * 256;   // M/256 = 32
    const int n0  = (wg & 15) * 256;   // N/256 = 16

    // ---- staging addresses (pre-swizzled source, linear LDS dest) ----
    const int rt = tid >> 3;
    const int ct = (tid & 7) ^ (rt & 7);
    const _Float16* sA = A  + (size_t)(m0 + rt) * IN_DIM + ct * 8;
    const _Float16* sB = Bw + (size_t)(n0 + rt) * IN_DIM + ct * 8;
    const int dstA = w * 1024;
    const int dstB = 32768 + w * 1024;

    // ---- fragment read offsets (swizzled) ----
    const int l15 = lane & 15, g = lane >> 4, l7 = lane & 7;
    const int s0 = (g ^ l7) << 4;            // slot byte for kb=0
    int aOffK[2], bOffK[2];
    aOffK[0] = (wm * 128 + l15) * 128 + s0;
    aOffK[1] = (wm * 128 + l15) * 128 + (s0 ^ 64);
    bOffK[0] = 32768 + (wn * 64 + l15) * 128 + s0;
    bOffK[1] = 32768 + (wn * 64 + l15) * 128 + (s0 ^ 64);

    f16x8 afrA[4][2], afrB[4][2], bfr[4][2];
    f32x4 acc[8][4] = {};

    // ---- prologue: kt0 -> buf0, kt1 -> buf1 ----
    #pragma unroll
    for (int R = 0; R < 4; ++R) { STAGE_A(0, R, 0); STAGE_B(0, R, 0); }
    #pragma unroll
    for (int R = 0; R < 4; ++R) { STAGE_A(1, R, 1); STAGE_B(1, R, 1); }
    WAIT_VM(8);     // buf0 landed (buf1's 8 still in flight)
    BAR();
    // pre-load P1's fragments
    LOAD_B(0, 0);
    LOAD_A_TO(afrA, 0, 0);

    #pragma unroll 1
    for (int it = 0; it < NI; ++it) {
        const int kt1 = 2 * it + 1;
        const int kt2 = (2 * it + 2) & (NT - 1);  // wraps harmlessly at tail
        const int kt3 = (2 * it + 3) & (NT - 1);

        // P1: MFMA Q(0,0)b0 [afrA] | read B(b0,nq1) | stage b1.B r2,3 (kt1)
        LOAD_B(0, 1);
        if (it) { STAGE_B(1, 2, kt1); STAGE_B(1, 3, kt1); }
        MFMA_Q(afrA, 0, 0);
        BAR();

        // P2: MFMA Q(0,1)b0 [afrA] | read A(b0,mq1)->afrB | stage b0.A r0,2 (kt2)
        LOAD_A_TO(afrB, 0, 1);
        STAGE_A(0, 0, kt2); STAGE_A(0, 2, kt2);
        MFMA_Q(afrA, 0, 1);
        BAR();

        // P3: MFMA Q(1,0)b0 [afrB] | stage b0.B r0,1 (kt2)
        STAGE_B(0, 0, kt2); STAGE_B(0, 1, kt2);
        MFMA_Q(afrB, 1, 0);
        BAR();

        // P4: vmcnt(4) | read B(b1,nq0)+A(b1,mq0)->afrA | stage b0.A r1,3 | MFMA Q(1,1)b0
        WAIT_VM(4);
        LOAD_B(1, 0);
        LOAD_A_TO(afrA, 1, 0);
        STAGE_A(0, 1, kt2); STAGE_A(0, 3, kt2);
        MFMA_Q(afrB, 1, 1);
        BAR();

        // P5: MFMA Q(0,0)b1 [afrA] | read B(b1,nq1) | stage b0.B r2,3 (kt2)
        LOAD_B(1, 1);
        STAGE_B(0, 2, kt2); STAGE_B(0, 3, kt2);
        MFMA_Q(afrA, 0, 0);
        BAR();

        // P6: MFMA Q(0,1)b1 [afrA] | read A(b1,mq1)->afrB | stage b1.A r0,2 (kt3)
        LOAD_A_TO(afrB, 1, 1);
        STAGE_A(1, 0, kt3); STAGE_A(1, 2, kt3);
        MFMA_Q(afrA, 0, 1);
        BAR();

        // P7: MFMA Q(1,0)b1 [afrB] | stage b1.B r0,1 (kt3)
        STAGE_B(1, 0, kt3); STAGE_B(1, 1, kt3);
        MFMA_Q(afrB, 1, 0);
        BAR();

        // P8: vmcnt(4) | read B(b0',nq0)+A(b0',mq0)->afrA | stage b1.A r1,3 | MFMA Q(1,1)b1
        WAIT_VM(4);
        LOAD_B(0, 0);
        LOAD_A_TO(afrA, 0, 0);
        STAGE_A(1, 1, kt3); STAGE_A(1, 3, kt3);
        MFMA_Q(afrB, 1, 1);
        BAR();
    }

    // ---- epilogue: dequant + rowsum*add + bias ----
    #pragma unroll
    for (int n = 0; n < 4; ++n) {
        const int col = n0 + wn * 64 + n * 16 + l15;
        const float sc = wscale[col];
        const float ad = wadd[col];
        const float bi = bias[col];
        #pragma unroll
        for (int m = 0; m < 8; ++m) {
            const int row = m0 + wm * 128 + m * 16 + g * 4;
            const float4 rs4 = *(const float4*)&rowsum[row];
            #pragma unroll
            for (int j = 0; j < 4; ++j) {
                const float rs = (j == 0) ? rs4.x : (j == 1) ? rs4.y : (j == 2) ? rs4.z : rs4.w;
                out[(size_t)(row + j) * OUT_DIM + col] = acc[m][n][j] * sc + ad * rs + bi;
            }
        }
    }
}

// ---------------------------------------------------------------------------
extern "C" void kernel_launch(void* const* d_in, const int* in_sizes, int n_in,
                              void* d_out, int out_size, void* d_ws, size_t ws_size,
                              hipStream_t stream)
{
    const float* x      = (const float*)d_in[0];
    const int*   wp     = (const int*)d_in[1];
    const float* wscale = (const float*)d_in[2];
    const float* wadd   = (const float*)d_in[3];
    const float* bias   = (const float*)d_in[4];
    float*       out    = (float*)d_out;

    const int M = in_sizes[0] / IN_DIM;   // 8192

    char* ws = (char*)d_ws;
    _Float16* wf = (_Float16*)ws;
    const size_t wf_bytes = (size_t)OUT_DIM * IN_DIM * sizeof(_Float16);
    _Float16* af = (_Float16*)(ws + wf_bytes);
    const size_t af_bytes = (size_t)M * IN_DIM * sizeof(_Float16);
    float* rowsum = (float*)(ws + wf_bytes + af_bytes);

    const int unpack_threads = OUT_DIM * (IN_DIM / 2) / 4;
    unpack_w<<<unpack_threads / 256, 256, 0, stream>>>(wp, wf);
    had_rows<<<M, 256, 0, stream>>>(x, af, rowsum);

    gemm8p<<<(M / 256) * (OUT_DIM / 256), 512, 0, stream>>>(
        af, wf, wscale, wadd, bias, rowsum, out);
}